// Round 7
// baseline (113.503 us; speedup 1.0000x reference)
//
#include <hip/hip_runtime.h>
#include <hip/hip_bf16.h>
#include <hip/hip_cooperative_groups.h>

namespace cg = cooperative_groups;

#define BN 8192
#define DIM 512
#define NB  64            // BN / 128 block-rows
#define NTILES 2080       // NB*(NB+1)/2 upper-triangle tiles
#define GRID 512          // cooperative grid: 2 blocks/CU x 256 CU
#define EPSF 1e-8f

using v8i   = __attribute__((ext_vector_type(8))) int;
using v4i   = __attribute__((ext_vector_type(4))) int;
using f32x4 = __attribute__((ext_vector_type(4))) float;

// Native exp2 (single v_exp_f32); fallback keeps exact semantics.
#if __has_builtin(__builtin_amdgcn_exp2f)
#define EXP2F(x) __builtin_amdgcn_exp2f(x)
#else
#define EXP2F(x) __expf((x) * 0.69314718055994531f)
#endif

// Async global->LDS, 16 B per lane, dest = uniform base + lane*16.
__device__ __forceinline__ void async_copy16(const void* g, void* l) {
    __builtin_amdgcn_global_load_lds(
        (const __attribute__((address_space(1))) void*)g,
        (__attribute__((address_space(3))) void*)l,
        16, 0, 0);
}

// ---------------------------------------------------------------------------
// Fused cooperative kernel: phase1 normalize -> grid.sync -> phase2
// persistent GEMM+epilogue over 2080 tiles (dynamic ticket) -> grid.sync ->
// phase3 finalize. Replaces 3 launches (each ~15-20us of launch/gap
// overhead, measured: 112us bench vs ~56us of device work) with 1.
// ---------------------------------------------------------------------------
__global__ __launch_bounds__(512, 4) void fused_kernel(
        const float* __restrict__ emb, const int* __restrict__ labels,
        unsigned char* __restrict__ E, int* __restrict__ cntG,
        int* __restrict__ ticketG, float* __restrict__ P,
        float* __restrict__ N, float* __restrict__ out) {
    // smem: A 4-plane (65536 B) overlaid with rowBuf [4][128][17]f2
    // (69632 B) + colBuf [4][2][128]f2 (8192 B) = 77824 B union.
    // Phase 3 aliases the same memory as fbuf[8][64]f2 (4 KB).
    __shared__ __attribute__((aligned(16))) unsigned char smem[77824];
    __shared__ int labI[128];
    __shared__ int labJ[128];
    __shared__ int nextT;

    const int tid  = threadIdx.x;
    const int bid  = blockIdx.x;
    const int wave = tid >> 6;          // 0..7
    const int lane = tid & 63;
    const int quad = lane >> 4;
    const int lrow = lane & 15;

    // ================= Phase 1: normalize (16 rows/block) =================
    if (bid == 0) {
        if (tid == 0) { out[0] = 0.f; *ticketG = GRID; }
        if (tid < 128) cntG[tid] = 0;
    }
    #pragma unroll
    for (int r = 0; r < 2; ++r) {
        int row = bid * 16 + wave * 2 + r;
        const float4* src = (const float4*)(emb + (size_t)row * DIM);
        float4 a = src[lane];
        float4 b = src[lane + 64];
        float ss = a.x*a.x + a.y*a.y + a.z*a.z + a.w*a.w
                 + b.x*b.x + b.y*b.y + b.z*b.z + b.w*b.w;
        #pragma unroll
        for (int m = 1; m < 64; m <<= 1) ss += __shfl_xor(ss, m, 64);
        float s4 = 4.0f / fmaxf(sqrtf(ss), 1e-12f);
        int pa = __builtin_amdgcn_cvt_pk_fp8_f32(a.x*s4, a.y*s4, 0, false);
        pa     = __builtin_amdgcn_cvt_pk_fp8_f32(a.z*s4, a.w*s4, pa, true);
        int pb = __builtin_amdgcn_cvt_pk_fp8_f32(b.x*s4, b.y*s4, 0, false);
        pb     = __builtin_amdgcn_cvt_pk_fp8_f32(b.z*s4, b.w*s4, pb, true);
        unsigned char* rowp = E + (size_t)row * DIM;
        ((unsigned*)rowp)[lane]         = (unsigned)pa;
        ((unsigned*)(rowp + 256))[lane] = (unsigned)pb;
    }

    cg::this_grid().sync();    // E + cntG/ticket init visible grid-wide

    // ====== Phase 2: persistent GEMM+epilogue (round-6 proven body) =======
    const int vC   = wave >> 2;         // i-half   (0..1)
    const int vQ   = wave & 3;          // j-quarter(0..3)
    const int i_w  = vC * 64;
    const int j_w  = vQ * 32;

    unsigned char* As = smem;                     // [4][128][128] planes
    float2* rowBuf = (float2*)smem;               // [4][128][17]
    float2* colBuf = (float2*)(smem + 69632);     // [4][2][128]

    const int stRow = lane >> 3;
    const int stChk = (lane & 7) ^ stRow;
    const int sw = lrow & 7;

    int t = bid;
    while (t < NTILES) {
        int bi = (int)(64.5f - sqrtf(64.5f * 64.5f - 2.0f * (float)t));
        while (64 * (bi + 1) - ((bi + 1) * bi) / 2 <= t) ++bi;
        while (64 * bi - (bi * (bi - 1)) / 2 > t) --bi;
        int bj = bi + (t - (64 * bi - (bi * (bi - 1)) / 2));
        const bool diag = (bi == bj);
        const int i0 = bi * 128;
        const int j0 = bj * 128;

        if (tid < 128)        labI[tid]       = labels[i0 + tid];
        else if (tid < 256)   labJ[tid - 128] = labels[j0 + tid - 128];
        // Diag tiles build the global label histogram (64 tiles x 128 rows
        // covers every row exactly once). Retired by the prologue vmcnt.
        if (diag && tid < 128) atomicAdd(&cntG[labels[i0 + tid]], 1);

        f32x4 acc[4][2];
        #pragma unroll
        for (int a = 0; a < 4; ++a)
            #pragma unroll
            for (int b = 0; b < 2; ++b)
                acc[a][b] = (f32x4){0.f, 0.f, 0.f, 0.f};

        const v4i* bptr[2];
        #pragma unroll
        for (int tj = 0; tj < 2; ++tj)
            bptr[tj] = (const v4i*)(E +
                (size_t)(j0 + j_w + tj * 16 + lrow) * DIM + quad * 32);

        const unsigned char* gA = E
            + (size_t)(i0 + wave * 16 + stRow) * DIM + stChk * 16;

        // Prologue: stage ALL 4 A-planes (8 instrs/wave), then B(0)
        // prefetch (4). vmcnt(4): staging (and the diag atomic) retired,
        // B0 still in flight. lgkmcnt(0) drains the label ds_writes.
        #pragma unroll
        for (int c = 0; c < 4; ++c)
            #pragma unroll
            for (int h = 0; h < 2; ++h)
                async_copy16(gA + (size_t)h * 8 * DIM + c * 128,
                             As + (size_t)c * 16384
                                + (size_t)(wave * 16 + h * 8) * 128);
        __builtin_amdgcn_sched_barrier(0);   // keep staging before B loads

        v8i bf[2][2];
        #pragma unroll
        for (int tj = 0; tj < 2; ++tj) {      // prefetch B for k=0
            ((v4i*)&bf[0][tj])[0] = bptr[tj][0];
            ((v4i*)&bf[0][tj])[1] = bptr[tj][1];
        }
        asm volatile("s_waitcnt vmcnt(4) lgkmcnt(0)" ::: "memory");
        __builtin_amdgcn_s_barrier();
        // ---- barrier-free k-loop: no staging, register-dep waits only ----

        #pragma unroll
        for (int k = 0; k < 4; ++k) {
            const int cur = k & 1;
            const unsigned char* bufC = As + (size_t)k * 16384;
            v8i af[4];
            #pragma unroll
            for (int ti = 0; ti < 4; ++ti) {
                int r = i_w + ti * 16 + lrow;
                const v4i* rp = (const v4i*)(bufC + (size_t)r * 128);
                ((v4i*)&af[ti])[0] = rp[(quad * 2) ^ sw];
                ((v4i*)&af[ti])[1] = rp[(quad * 2 + 1) ^ sw];
            }
            if (k < 3) {                      // prefetch next k's B
                #pragma unroll
                for (int tj = 0; tj < 2; ++tj) {
                    ((v4i*)&bf[cur ^ 1][tj])[0] = bptr[tj][(k + 1) * 8];
                    ((v4i*)&bf[cur ^ 1][tj])[1] = bptr[tj][(k + 1) * 8 + 1];
                }
            }
            #pragma unroll
            for (int ti = 0; ti < 4; ++ti)
                #pragma unroll
                for (int tj = 0; tj < 2; ++tj)
                    acc[ti][tj] =
                        __builtin_amdgcn_mfma_scale_f32_16x16x128_f8f6f4(
                            af[ti], bf[cur][tj], acc[ti][tj],
                            0, 0,                 // fp8 e4m3 / e4m3
                            0, 0x7F7F7F7F,        // A scale = 1.0
                            0, 0x7F7F7F7F);       // B scale = 1.0
        }
        __syncthreads();   // all waves done reading As -> overlay writable

        // Epilogue. C/D: col = lane&15, row = quad*4 + reg. acc = 16*S.
        const float K1 = 0.0901619783824569f;    // log2(e)/16
        const float K2 = -1.4426950408889634f;   // -log2(e)
        if (!diag) {
            float psC[2] = {0.f, 0.f};
            float tsC[2] = {0.f, 0.f};
            #pragma unroll
            for (int ti = 0; ti < 4; ++ti) {
                #pragma unroll
                for (int reg = 0; reg < 4; ++reg) {
                    int irow = i_w + ti * 16 + quad * 4 + reg;
                    int li   = labI[irow];
                    float ps = 0.f, ts = 0.f;
                    #pragma unroll
                    for (int tj = 0; tj < 2; ++tj) {
                        int jcol = j_w + tj * 16 + lrow;
                        float w  = EXP2F(fmaf(acc[ti][tj][reg], K1, K2));
                        float wp = (li == labJ[jcol]) ? w : 0.f;
                        ps += wp;  ts += w;
                        psC[tj] += wp;  tsC[tj] += w;
                    }
                    rowBuf[(size_t)(vQ * 128 + irow) * 17 + lrow] =
                        (float2){ps, ts - ps};
                }
            }
            #pragma unroll
            for (int tj = 0; tj < 2; ++tj) {
                int jcol = j_w + tj * 16 + lrow;
                colBuf[(size_t)(quad * 2 + vC) * 128 + jcol] =
                    (float2){psC[tj], tsC[tj] - psC[tj]};
            }
        } else {
            #pragma unroll
            for (int ti = 0; ti < 4; ++ti) {
                #pragma unroll
                for (int reg = 0; reg < 4; ++reg) {
                    int irow = i_w + ti * 16 + quad * 4 + reg;
                    int li   = labI[irow];
                    float ps = 0.f, ts = 0.f, sf = 0.f;
                    #pragma unroll
                    for (int tj = 0; tj < 2; ++tj) {
                        int jcol = j_w + tj * 16 + lrow;
                        float w  = EXP2F(fmaf(acc[ti][tj][reg], K1, K2));
                        float wp = (li == labJ[jcol]) ? w : 0.f;
                        float wd = (irow == jcol) ? w : 0.f;
                        ps += wp;  ts += w;  sf += wd;
                    }
                    rowBuf[(size_t)(vQ * 128 + irow) * 17 + lrow] =
                        (float2){ps - sf, ts - ps};
                }
            }
        }
        __syncthreads();

        if (tid < 128) {
            float sp = 0.f, sn = 0.f;
            #pragma unroll
            for (int vq = 0; vq < 4; ++vq) {
                const float2* a = rowBuf + (size_t)(vq * 128 + tid) * 17;
                #pragma unroll
                for (int u = 0; u < 16; ++u) {
                    sp += a[u].x;
                    sn += a[u].y;
                }
            }
            P[(size_t)bj * BN + i0 + tid] = sp;
            N[(size_t)bj * BN + i0 + tid] = sn;
        } else if (tid < 256 && !diag) {
            int c2 = tid - 128;
            float sp = 0.f, sn = 0.f;
            #pragma unroll
            for (int s = 0; s < 8; ++s) {
                float2 a = colBuf[(size_t)s * 128 + c2];
                sp += a.x;
                sn += a.y;
            }
            P[(size_t)bi * BN + j0 + c2] = sp;
            N[(size_t)bi * BN + j0 + c2] = sn;
        }
        __syncthreads();                       // smem reads done; safe to reuse
        if (tid == 0) nextT = atomicAdd(ticketG, 1);
        __syncthreads();
        t = nextT;
    }

    cg::this_grid().sync();    // P/N + histogram visible grid-wide

    // ================= Phase 3: finalize (blocks 0..127) ==================
    if (bid < 128) {
        float2* fbuf = (float2*)smem;          // [8][64]
        int r = tid & 63, w = wave;
        int i = bid * 64 + r;
        float p = 0.f, n = 0.f;
        #pragma unroll
        for (int u = 0; u < 8; ++u) {
            int c = w + u * 8;
            p += P[(size_t)c * BN + i];
            n += N[(size_t)c * BN + i];
        }
        fbuf[w * 64 + r] = (float2){p, n};
        __syncthreads();
        if (tid < 64) {
            p = 0.f; n = 0.f;
            #pragma unroll
            for (int s = 0; s < 8; ++s) {
                float2 a = fbuf[s * 64 + r];
                p += a.x;  n += a.y;
            }
            int   cl = cntG[labels[i]];
            float pm = p / fmaxf((float)(cl - 1), 1.0f);
            float nm = n / fmaxf((float)(BN - cl), 1.0f);
            float v  = ((cl - 1 > 0) && (BN - cl > 0))
                           ? -logf(pm / (pm + nm + EPSF)) : 0.0f;
            v *= (1.0f / (float)BN);
            #pragma unroll
            for (int m = 1; m < 64; m <<= 1) v += __shfl_xor(v, m, 64);
            if (r == 0) atomicAdd(out, v);
        }
    }
}

// ---------------------------------------------------------------------------
// Fallback path (proven round-6 kernels) in case cooperative co-residency
// validation fails on this device/runtime.
// ---------------------------------------------------------------------------
__global__ __launch_bounds__(256) void normalize_kernel(
        const float* __restrict__ emb, unsigned char* __restrict__ E,
        int* __restrict__ cntG, float* __restrict__ out) {
    if (blockIdx.x == 0) {
        if (threadIdx.x == 0) out[0] = 0.f;
        if (threadIdx.x < 128) cntG[threadIdx.x] = 0;
    }
    int lane = threadIdx.x & 63;
    int row  = blockIdx.x * 4 + (threadIdx.x >> 6);
    const float4* src = (const float4*)(emb + (size_t)row * DIM);
    float4 a = src[lane];
    float4 b = src[lane + 64];
    float ss = a.x*a.x + a.y*a.y + a.z*a.z + a.w*a.w
             + b.x*b.x + b.y*b.y + b.z*b.z + b.w*b.w;
    #pragma unroll
    for (int m = 1; m < 64; m <<= 1) ss += __shfl_xor(ss, m, 64);
    float s4 = 4.0f / fmaxf(sqrtf(ss), 1e-12f);
    int pa = __builtin_amdgcn_cvt_pk_fp8_f32(a.x*s4, a.y*s4, 0, false);
    pa     = __builtin_amdgcn_cvt_pk_fp8_f32(a.z*s4, a.w*s4, pa, true);
    int pb = __builtin_amdgcn_cvt_pk_fp8_f32(b.x*s4, b.y*s4, 0, false);
    pb     = __builtin_amdgcn_cvt_pk_fp8_f32(b.z*s4, b.w*s4, pb, true);
    unsigned char* rowp = E + (size_t)row * DIM;
    ((unsigned*)rowp)[lane]         = (unsigned)pa;
    ((unsigned*)(rowp + 256))[lane] = (unsigned)pb;
}

__global__ __launch_bounds__(512, 4) void gemm_epi_kernel(
        const unsigned char* __restrict__ E, const int* __restrict__ labels,
        int* __restrict__ cntG, float* __restrict__ P, float* __restrict__ N) {
    __shared__ __attribute__((aligned(16))) unsigned char smem[77824];
    __shared__ int labI[128];
    __shared__ int labJ[128];

    int t  = blockIdx.x;
    int bi = (int)(64.5f - sqrtf(64.5f * 64.5f - 2.0f * (float)t));
    while (64 * (bi + 1) - ((bi + 1) * bi) / 2 <= t) ++bi;
    while (64 * bi - (bi * (bi - 1)) / 2 > t) --bi;
    int bj = bi + (t - (64 * bi - (bi * (bi - 1)) / 2));
    const bool diag = (bi == bj);
    const int i0 = bi * 128;
    const int j0 = bj * 128;

    const int tid  = threadIdx.x;
    const int wave = tid >> 6;
    const int lane = tid & 63;
    const int quad = lane >> 4;
    const int lrow = lane & 15;
    const int vC   = wave >> 2;
    const int vQ   = wave & 3;
    const int i_w  = vC * 64;
    const int j_w  = vQ * 32;

    if (tid < 128)        labI[tid]       = labels[i0 + tid];
    else if (tid < 256)   labJ[tid - 128] = labels[j0 + tid - 128];
    if (diag && tid < 128) atomicAdd(&cntG[labels[i0 + tid]], 1);

    unsigned char* As = smem;
    float2* rowBuf = (float2*)smem;
    float2* colBuf = (float2*)(smem + 69632);

    f32x4 acc[4][2];
    #pragma unroll
    for (int a = 0; a < 4; ++a)
        #pragma unroll
        for (int b = 0; b < 2; ++b)
            acc[a][b] = (f32x4){0.f, 0.f, 0.f, 0.f};

    const v4i* bptr[2];
    #pragma unroll
    for (int tj = 0; tj < 2; ++tj)
        bptr[tj] = (const v4i*)(E +
            (size_t)(j0 + j_w + tj * 16 + lrow) * DIM + quad * 32);

    const int stRow = lane >> 3;
    const int stChk = (lane & 7) ^ stRow;
    const unsigned char* gA = E + (size_t)(i0 + wave * 16 + stRow) * DIM
                                + stChk * 16;
    const int sw = lrow & 7;

    #pragma unroll
    for (int c = 0; c < 4; ++c)
        #pragma unroll
        for (int h = 0; h < 2; ++h)
            async_copy16(gA + (size_t)h * 8 * DIM + c * 128,
                         As + (size_t)c * 16384
                            + (size_t)(wave * 16 + h * 8) * 128);
    __builtin_amdgcn_sched_barrier(0);

    v8i bf[2][2];
    #pragma unroll
    for (int tj = 0; tj < 2; ++tj) {
        ((v4i*)&bf[0][tj])[0] = bptr[tj][0];
        ((v4i*)&bf[0][tj])[1] = bptr[tj][1];
    }
    asm volatile("s_waitcnt vmcnt(4) lgkmcnt(0)" ::: "memory");
    __builtin_amdgcn_s_barrier();

    #pragma unroll
    for (int k = 0; k < 4; ++k) {
        const int cur = k & 1;
        const unsigned char* bufC = As + (size_t)k * 16384;
        v8i af[4];
        #pragma unroll
        for (int ti = 0; ti < 4; ++ti) {
            int r  = i_w + ti * 16 + lrow;
            const v4i* rp = (const v4i*)(bufC + (size_t)r * 128);
            ((v4i*)&af[ti])[0] = rp[(quad * 2) ^ sw];
            ((v4i*)&af[ti])[1] = rp[(quad * 2 + 1) ^ sw];
        }
        if (k < 3) {
            #pragma unroll
            for (int tj = 0; tj < 2; ++tj) {
                ((v4i*)&bf[cur ^ 1][tj])[0] = bptr[tj][(k + 1) * 8];
                ((v4i*)&bf[cur ^ 1][tj])[1] = bptr[tj][(k + 1) * 8 + 1];
            }
        }
        #pragma unroll
        for (int ti = 0; ti < 4; ++ti)
            #pragma unroll
            for (int tj = 0; tj < 2; ++tj)
                acc[ti][tj] =
                    __builtin_amdgcn_mfma_scale_f32_16x16x128_f8f6f4(
                        af[ti], bf[cur][tj], acc[ti][tj],
                        0, 0, 0, 0x7F7F7F7F, 0, 0x7F7F7F7F);
    }
    __syncthreads();

    const float K1 = 0.0901619783824569f;
    const float K2 = -1.4426950408889634f;
    if (!diag) {
        float psC[2] = {0.f, 0.f};
        float tsC[2] = {0.f, 0.f};
        #pragma unroll
        for (int ti = 0; ti < 4; ++ti) {
            #pragma unroll
            for (int reg = 0; reg < 4; ++reg) {
                int irow = i_w + ti * 16 + quad * 4 + reg;
                int li   = labI[irow];
                float ps = 0.f, ts = 0.f;
                #pragma unroll
                for (int tj = 0; tj < 2; ++tj) {
                    int jcol = j_w + tj * 16 + lrow;
                    float w  = EXP2F(fmaf(acc[ti][tj][reg], K1, K2));
                    float wp = (li == labJ[jcol]) ? w : 0.f;
                    ps += wp;  ts += w;
                    psC[tj] += wp;  tsC[tj] += w;
                }
                rowBuf[(size_t)(vQ * 128 + irow) * 17 + lrow] =
                    (float2){ps, ts - ps};
            }
        }
        #pragma unroll
        for (int tj = 0; tj < 2; ++tj) {
            int jcol = j_w + tj * 16 + lrow;
            colBuf[(size_t)(quad * 2 + vC) * 128 + jcol] =
                (float2){psC[tj], tsC[tj] - psC[tj]};
        }
    } else {
        #pragma unroll
        for (int ti = 0; ti < 4; ++ti) {
            #pragma unroll
            for (int reg = 0; reg < 4; ++reg) {
                int irow = i_w + ti * 16 + quad * 4 + reg;
                int li   = labI[irow];
                float ps = 0.f, ts = 0.f, sf = 0.f;
                #pragma unroll
                for (int tj = 0; tj < 2; ++tj) {
                    int jcol = j_w + tj * 16 + lrow;
                    float w  = EXP2F(fmaf(acc[ti][tj][reg], K1, K2));
                    float wp = (li == labJ[jcol]) ? w : 0.f;
                    float wd = (irow == jcol) ? w : 0.f;
                    ps += wp;  ts += w;  sf += wd;
                }
                rowBuf[(size_t)(vQ * 128 + irow) * 17 + lrow] =
                    (float2){ps - sf, ts - ps};
            }
        }
    }
    __syncthreads();

    if (tid < 128) {
        float sp = 0.f, sn = 0.f;
        #pragma unroll
        for (int vq = 0; vq < 4; ++vq) {
            const float2* a = rowBuf + (size_t)(vq * 128 + tid) * 17;
            #pragma unroll
            for (int u = 0; u < 16; ++u) {
                sp += a[u].x;
                sn += a[u].y;
            }
        }
        P[(size_t)bj * BN + i0 + tid] = sp;
        N[(size_t)bj * BN + i0 + tid] = sn;
    } else if (tid < 256 && !diag) {
        int c2 = tid - 128;
        float sp = 0.f, sn = 0.f;
        #pragma unroll
        for (int s = 0; s < 8; ++s) {
            float2 a = colBuf[(size_t)s * 128 + c2];
            sp += a.x;
            sn += a.y;
        }
        P[(size_t)bi * BN + j0 + c2] = sp;
        N[(size_t)bi * BN + j0 + c2] = sn;
    }
}

__global__ __launch_bounds__(256) void reduce_finalize_kernel(
        const int* __restrict__ labels, const float* __restrict__ P,
        const float* __restrict__ N, const int* __restrict__ cntG,
        float* __restrict__ out) {
    __shared__ float2 buf[4][64];
    int tid = threadIdx.x;
    int r = tid & 63, w = tid >> 6;
    int i = blockIdx.x * 64 + r;
    float p = 0.f, n = 0.f;
    #pragma unroll
    for (int u = 0; u < 16; ++u) {
        int c = w + u * 4;
        p += P[(size_t)c * BN + i];
        n += N[(size_t)c * BN + i];
    }
    buf[w][r] = (float2){p, n};
    __syncthreads();
    if (tid < 64) {
        float2 s0 = buf[0][r], s1 = buf[1][r], s2 = buf[2][r], s3 = buf[3][r];
        p = s0.x + s1.x + s2.x + s3.x;
        n = s0.y + s1.y + s2.y + s3.y;
        int   cl = cntG[labels[i]];
        float pm = p / fmaxf((float)(cl - 1), 1.0f);
        float nm = n / fmaxf((float)(BN - cl), 1.0f);
        float v  = ((cl - 1 > 0) && (BN - cl > 0))
                       ? -logf(pm / (pm + nm + EPSF)) : 0.0f;
        v *= (1.0f / (float)BN);
        #pragma unroll
        for (int m = 1; m < 64; m <<= 1) v += __shfl_xor(v, m, 64);
        if (r == 0) atomicAdd(out, v);
    }
}

extern "C" void kernel_launch(void* const* d_in, const int* in_sizes, int n_in,
                              void* d_out, int out_size, void* d_ws, size_t ws_size,
                              hipStream_t stream) {
    const float* emb   = (const float*)d_in[0];
    const int* labels  = (const int*)d_in[1];
    float* out         = (float*)d_out;

    // ws layout: E (8 MB reserved; fp8 uses 4; cnt+ticket live at +4 MB) |
    // P (2 MB) | N (2 MB)
    unsigned char* E   = (unsigned char*)d_ws;
    int* cntG          = (int*)((char*)d_ws + (size_t)BN * DIM);
    int* ticketG       = cntG + 128;
    float* P           = (float*)((char*)d_ws + (size_t)BN * DIM * 2);
    float* N           = P + (size_t)NB * BN;

    // One-time host-side occupancy check (capture-safe: no stream ops).
    static int coop_ok = -1;
    if (coop_ok < 0) {
        int nb = 0;
        hipError_t e = hipOccupancyMaxActiveBlocksPerMultiprocessor(
            &nb, fused_kernel, 512, 0);
        coop_ok = (e == hipSuccess && nb >= 2) ? 1 : 0;
    }

    if (coop_ok) {
        void* args[] = {(void*)&emb, (void*)&labels, (void*)&E, (void*)&cntG,
                        (void*)&ticketG, (void*)&P, (void*)&N, (void*)&out};
        hipLaunchCooperativeKernel((void*)fused_kernel, dim3(GRID), dim3(512),
                                   args, 0, stream);
    } else {
        normalize_kernel<<<BN / 4, 256, 0, stream>>>(emb, E, cntG, out);
        gemm_epi_kernel<<<NTILES, 512, 0, stream>>>(E, labels, cntG, P, N);
        reduce_finalize_kernel<<<128, 256, 0, stream>>>(labels, P, N, cntG, out);
    }
}

// Round 8
// 110.498 us; speedup vs baseline: 1.0272x; 1.0272x over previous
//
#include <hip/hip_runtime.h>
#include <hip/hip_bf16.h>

#define BN 8192
#define DIM 512
#define NB  64            // BN / 128 block-rows
#define NTILES 2080       // NB*(NB+1)/2 upper-triangle tiles
#define EPSF 1e-8f

using v8i   = __attribute__((ext_vector_type(8))) int;
using v4i   = __attribute__((ext_vector_type(4))) int;
using f32x4 = __attribute__((ext_vector_type(4))) float;

// Native exp2 (single v_exp_f32); fallback keeps exact semantics.
#if __has_builtin(__builtin_amdgcn_exp2f)
#define EXP2F(x) __builtin_amdgcn_exp2f(x)
#else
#define EXP2F(x) __expf((x) * 0.69314718055994531f)
#endif

// Async global->LDS, 16 B per lane, dest = uniform base + lane*16.
__device__ __forceinline__ void async_copy16(const void* g, void* l) {
    __builtin_amdgcn_global_load_lds(
        (const __attribute__((address_space(1))) void*)g,
        (__attribute__((address_space(3))) void*)l,
        16, 0, 0);
}

// One wave per row: L2-normalize, x4 pre-scale, fp8 e4m3; out[0] and the
// global label-count array zeroed by block 0 (cnt is filled by gemm's diag
// blocks, read by finalize -- all stream-ordered).
__global__ __launch_bounds__(256) void normalize_kernel(
        const float* __restrict__ emb, unsigned char* __restrict__ E,
        int* __restrict__ cntG, float* __restrict__ out) {
    if (blockIdx.x == 0) {
        if (threadIdx.x == 0) out[0] = 0.f;
        if (threadIdx.x < 128) cntG[threadIdx.x] = 0;
    }
    int lane = threadIdx.x & 63;
    int row  = blockIdx.x * 4 + (threadIdx.x >> 6);
    const float4* src = (const float4*)(emb + (size_t)row * DIM);
    float4 a = src[lane];
    float4 b = src[lane + 64];
    float ss = a.x*a.x + a.y*a.y + a.z*a.z + a.w*a.w
             + b.x*b.x + b.y*b.y + b.z*b.z + b.w*b.w;
    #pragma unroll
    for (int m = 1; m < 64; m <<= 1) ss += __shfl_xor(ss, m, 64);
    float s4 = 4.0f / fmaxf(sqrtf(ss), 1e-12f);
    int pa = __builtin_amdgcn_cvt_pk_fp8_f32(a.x*s4, a.y*s4, 0, false);
    pa     = __builtin_amdgcn_cvt_pk_fp8_f32(a.z*s4, a.w*s4, pa, true);
    int pb = __builtin_amdgcn_cvt_pk_fp8_f32(b.x*s4, b.y*s4, 0, false);
    pb     = __builtin_amdgcn_cvt_pk_fp8_f32(b.z*s4, b.w*s4, pb, true);
    unsigned char* rowp = E + (size_t)row * DIM;
    ((unsigned*)rowp)[lane]         = (unsigned)pa;
    ((unsigned*)(rowp + 256))[lane] = (unsigned)pb;
}

// Upper-triangle 128x128 tiles, 1D grid (2080), triangular decode.
// fp8 MX MFMA 16x16x128. 512-thread blocks (8 waves), wave (vC,vQ) owns a
// 64x32 output (4x2 of 16x16). Round-6 structure (whole-tile A staging,
// ONE barrier, barrier-free k-loop) + round-8 changes:
//  (a) B prefetch deepened to TWO k-steps (3 live register buffers,
//      statically indexed in the unrolled loop): B gather L2 latency
//      (~200-400cy) was covered by only ~70-140cy at depth 1 -- the
//      per-wave stall that pinned MfmaUtil at 13%.
//  (b) s_setprio(1) around the MFMA cluster: independent-wave regime
//      (no in-loop barriers), where setprio measured +4-7%.
// Register budget: acc 32 AGPR + B 3x16=48 VGPR + af 32 transient =>
// ~100-116 unified, still >= 4 waves/SIMD (launch_bounds(512,4));
// occupancy stays LDS-bound at 2 blocks/CU.
__global__ __launch_bounds__(512, 4) void gemm_epi_kernel(
        const unsigned char* __restrict__ E, const int* __restrict__ labels,
        int* __restrict__ cntG, float* __restrict__ P, float* __restrict__ N) {
    // smem: A 4-plane (65536 B) overlaid with rowBuf [4][128][17]f2
    // (69632 B) + colBuf [4][2][128]f2 (8192 B) = 77824 B union.
    __shared__ __attribute__((aligned(16))) unsigned char smem[77824];
    __shared__ int labI[128];
    __shared__ int labJ[128];

    int t  = blockIdx.x;
    int bi = (int)(64.5f - sqrtf(64.5f * 64.5f - 2.0f * (float)t));
    while (64 * (bi + 1) - ((bi + 1) * bi) / 2 <= t) ++bi;
    while (64 * bi - (bi * (bi - 1)) / 2 > t) --bi;
    int bj = bi + (t - (64 * bi - (bi * (bi - 1)) / 2));
    const bool diag = (bi == bj);
    const int i0 = bi * 128;
    const int j0 = bj * 128;

    const int tid  = threadIdx.x;
    const int wave = tid >> 6;          // 0..7
    const int lane = tid & 63;
    const int quad = lane >> 4;
    const int lrow = lane & 15;
    const int vC   = wave >> 2;         // i-half   (0..1)
    const int vQ   = wave & 3;          // j-quarter(0..3)
    const int i_w  = vC * 64;
    const int j_w  = vQ * 32;

    if (tid < 128)        labI[tid]       = labels[i0 + tid];
    else if (tid < 256)   labJ[tid - 128] = labels[j0 + tid - 128];
    // Diag blocks build the global label histogram (64 blocks x 128 rows
    // covers every row exactly once). Retired by the prologue vmcnt.
    if (diag && tid < 128) atomicAdd(&cntG[labels[i0 + tid]], 1);

    unsigned char* As = smem;                     // [4][128][128] planes
    float2* rowBuf = (float2*)smem;               // [4][128][17]
    float2* colBuf = (float2*)(smem + 69632);     // [4][2][128]

    f32x4 acc[4][2];
    #pragma unroll
    for (int a = 0; a < 4; ++a)
        #pragma unroll
        for (int b = 0; b < 2; ++b)
            acc[a][b] = (f32x4){0.f, 0.f, 0.f, 0.f};

    const v4i* bptr[2];
    #pragma unroll
    for (int tj = 0; tj < 2; ++tj)
        bptr[tj] = (const v4i*)(E +
            (size_t)(j0 + j_w + tj * 16 + lrow) * DIM + quad * 32);

    // Staging lane constants: each wave covers rows [wave*16, wave*16+16),
    // 2 instrs x 8 rows per plane; lane l -> row (l>>3), LDS chunk l&7
    // holds global chunk (l&7)^(l>>3) (row&7 == l>>3, bases multiple of 8).
    const int stRow = lane >> 3;
    const int stChk = (lane & 7) ^ stRow;
    const unsigned char* gA = E + (size_t)(i0 + wave * 16 + stRow) * DIM
                                + stChk * 16;
    const int sw = lrow & 7;

    // Prologue: stage ALL 4 A-planes (8 instrs/wave), then B0+B1 prefetch
    // (8 loads). vmcnt(8): the 8 staging instrs (and the diag atomic)
    // retired, B0/B1 still in flight. lgkmcnt(0) drains label ds_writes.
    #pragma unroll
    for (int c = 0; c < 4; ++c)
        #pragma unroll
        for (int h = 0; h < 2; ++h)
            async_copy16(gA + (size_t)h * 8 * DIM + c * 128,
                         As + (size_t)c * 16384
                            + (size_t)(wave * 16 + h * 8) * 128);
    __builtin_amdgcn_sched_barrier(0);   // keep staging before B loads

    v8i bf[3][2];                         // 3-deep circular B buffer
    #pragma unroll
    for (int kk = 0; kk < 2; ++kk)        // prefetch B for k=0,1
        #pragma unroll
        for (int tj = 0; tj < 2; ++tj) {
            ((v4i*)&bf[kk][tj])[0] = bptr[tj][kk * 8];
            ((v4i*)&bf[kk][tj])[1] = bptr[tj][kk * 8 + 1];
        }
    asm volatile("s_waitcnt vmcnt(8) lgkmcnt(0)" ::: "memory");
    __builtin_amdgcn_s_barrier();
    // ---- from here to the epilogue sync: NO barriers, NO staging ----

    #pragma unroll
    for (int k = 0; k < 4; ++k) {
        const int cur = k % 3;            // k is a compile-time constant
        const unsigned char* bufC = As + (size_t)k * 16384;
        if (k < 2) {                      // issue B(k+2), TWO k-steps ahead
            const int nb = (k + 2) % 3;
            #pragma unroll
            for (int tj = 0; tj < 2; ++tj) {
                ((v4i*)&bf[nb][tj])[0] = bptr[tj][(k + 2) * 8];
                ((v4i*)&bf[nb][tj])[1] = bptr[tj][(k + 2) * 8 + 1];
            }
        }
        v8i af[4];
        #pragma unroll
        for (int ti = 0; ti < 4; ++ti) {
            int r  = i_w + ti * 16 + lrow;
            const v4i* rp = (const v4i*)(bufC + (size_t)r * 128);
            ((v4i*)&af[ti])[0] = rp[(quad * 2) ^ sw];
            ((v4i*)&af[ti])[1] = rp[(quad * 2 + 1) ^ sw];
        }
        __builtin_amdgcn_s_setprio(1);
        #pragma unroll
        for (int ti = 0; ti < 4; ++ti)
            #pragma unroll
            for (int tj = 0; tj < 2; ++tj)
                acc[ti][tj] =
                    __builtin_amdgcn_mfma_scale_f32_16x16x128_f8f6f4(
                        af[ti], bf[cur][tj], acc[ti][tj],
                        0, 0,                 // fp8 e4m3 / e4m3
                        0, 0x7F7F7F7F,        // A scale = 1.0
                        0, 0x7F7F7F7F);       // B scale = 1.0
        __builtin_amdgcn_s_setprio(0);
    }
    __syncthreads();      // all waves done reading As -> overlay writable

    // Epilogue. C/D: col = lane&15, row = quad*4 + reg. acc = 16*S.
    // w = exp(S-1) = exp2(acc*K1 + K2). 32 elements/thread.
    const float K1 = 0.0901619783824569f;    // log2(e)/16
    const float K2 = -1.4426950408889634f;   // -log2(e)
    if (!diag) {
        float psC[2] = {0.f, 0.f};
        float tsC[2] = {0.f, 0.f};
        #pragma unroll
        for (int ti = 0; ti < 4; ++ti) {
            #pragma unroll
            for (int reg = 0; reg < 4; ++reg) {
                int irow = i_w + ti * 16 + quad * 4 + reg;
                int li   = labI[irow];
                float ps = 0.f, ts = 0.f;
                #pragma unroll
                for (int tj = 0; tj < 2; ++tj) {
                    int jcol = j_w + tj * 16 + lrow;
                    float w  = EXP2F(fmaf(acc[ti][tj][reg], K1, K2));
                    float wp = (li == labJ[jcol]) ? w : 0.f;
                    ps += wp;  ts += w;
                    psC[tj] += wp;  tsC[tj] += w;
                }
                rowBuf[(size_t)(vQ * 128 + irow) * 17 + lrow] =
                    (float2){ps, ts - ps};
            }
        }
        #pragma unroll
        for (int tj = 0; tj < 2; ++tj) {
            int jcol = j_w + tj * 16 + lrow;
            colBuf[(size_t)(quad * 2 + vC) * 128 + jcol] =
                (float2){psC[tj], tsC[tj] - psC[tj]};
        }
    } else {
        // Diag tile: self pair (irow == jcol) excluded from pos exactly;
        // col sums unused (row path covers the full square).
        #pragma unroll
        for (int ti = 0; ti < 4; ++ti) {
            #pragma unroll
            for (int reg = 0; reg < 4; ++reg) {
                int irow = i_w + ti * 16 + quad * 4 + reg;
                int li   = labI[irow];
                float ps = 0.f, ts = 0.f, sf = 0.f;
                #pragma unroll
                for (int tj = 0; tj < 2; ++tj) {
                    int jcol = j_w + tj * 16 + lrow;
                    float w  = EXP2F(fmaf(acc[ti][tj][reg], K1, K2));
                    float wp = (li == labJ[jcol]) ? w : 0.f;
                    float wd = (irow == jcol) ? w : 0.f;
                    ps += wp;  ts += w;  sf += wd;
                }
                rowBuf[(size_t)(vQ * 128 + irow) * 17 + lrow] =
                    (float2){ps - sf, ts - ps};
            }
        }
    }
    __syncthreads();

    if (tid < 128) {
        float sp = 0.f, sn = 0.f;
        #pragma unroll
        for (int vq = 0; vq < 4; ++vq) {
            const float2* a = rowBuf + (size_t)(vq * 128 + tid) * 17;
            #pragma unroll
            for (int u = 0; u < 16; ++u) {
                sp += a[u].x;
                sn += a[u].y;
            }
        }
        P[(size_t)bj * BN + i0 + tid] = sp;
        N[(size_t)bj * BN + i0 + tid] = sn;
    } else if (tid < 256 && !diag) {
        int c2 = tid - 128;
        float sp = 0.f, sn = 0.f;
        #pragma unroll
        for (int s = 0; s < 8; ++s) {
            float2 a = colBuf[(size_t)s * 128 + c2];
            sp += a.x;
            sn += a.y;
        }
        P[(size_t)bi * BN + j0 + c2] = sp;
        N[(size_t)bi * BN + j0 + c2] = sn;
    }
}

// Fused tail: 128 blocks x 256. Each block owns 64 rows; the 4 waves split
// the 64 column-blocks (16 strided, coalesced 256B/wave), LDS combine,
// per-row loss (histogram read from precomputed global cnt), one
// atomicAdd of the pre-scaled block sum into out[0].
__global__ __launch_bounds__(256) void reduce_finalize_kernel(
        const int* __restrict__ labels, const float* __restrict__ P,
        const float* __restrict__ N, const int* __restrict__ cntG,
        float* __restrict__ out) {
    __shared__ float2 buf[4][64];
    int tid = threadIdx.x;
    int r = tid & 63, w = tid >> 6;
    int i = blockIdx.x * 64 + r;
    float p = 0.f, n = 0.f;
    #pragma unroll
    for (int u = 0; u < 16; ++u) {
        int c = w + u * 4;
        p += P[(size_t)c * BN + i];
        n += N[(size_t)c * BN + i];
    }
    buf[w][r] = (float2){p, n};
    __syncthreads();
    if (tid < 64) {
        float2 s0 = buf[0][r], s1 = buf[1][r], s2 = buf[2][r], s3 = buf[3][r];
        p = s0.x + s1.x + s2.x + s3.x;
        n = s0.y + s1.y + s2.y + s3.y;
        int   cl = cntG[labels[i]];
        float pm = p / fmaxf((float)(cl - 1), 1.0f);
        float nm = n / fmaxf((float)(BN - cl), 1.0f);
        float v  = ((cl - 1 > 0) && (BN - cl > 0))
                       ? -logf(pm / (pm + nm + EPSF)) : 0.0f;
        v *= (1.0f / (float)BN);
        #pragma unroll
        for (int m = 1; m < 64; m <<= 1) v += __shfl_xor(v, m, 64);
        if (r == 0) atomicAdd(out, v);
    }
}

extern "C" void kernel_launch(void* const* d_in, const int* in_sizes, int n_in,
                              void* d_out, int out_size, void* d_ws, size_t ws_size,
                              hipStream_t stream) {
    const float* emb   = (const float*)d_in[0];
    const int* labels  = (const int*)d_in[1];
    float* out         = (float*)d_out;

    // ws layout: E (8 MB reserved; fp8 uses 4, cnt lives at +4 MB) |
    // P (2 MB) | N (2 MB)
    unsigned char* E   = (unsigned char*)d_ws;
    int* cntG          = (int*)((char*)d_ws + (size_t)BN * DIM);
    float* P           = (float*)((char*)d_ws + (size_t)BN * DIM * 2);
    float* N           = P + (size_t)NB * BN;

    normalize_kernel<<<BN / 4, 256, 0, stream>>>(emb, E, cntG, out);
    gemm_epi_kernel<<<NTILES, 512, 0, stream>>>(E, labels, cntG, P, N);
    reduce_finalize_kernel<<<128, 256, 0, stream>>>(labels, P, N, cntG, out);
}